// Round 14
// baseline (109.685 us; speedup 1.0000x reference)
//
#include <hip/hip_runtime.h>
#include <stdint.h>
#include <stddef.h>

// ---------------------------------------------------------------------------
// GraphSAGE supervised forward (B=1024, D=HID=128, fanout 25/10, classes 64)
// Round 14: DIAGNOSTIC — r13 byte-identical, but gemm_l1 launched 3x; first
// two write to dummy buffers (never read -> output unchanged).
// dur - 71.1 = 2*(T_gemm + gap). Pins the unexplained ~40us residual.
// ---------------------------------------------------------------------------

typedef short bf16x8v __attribute__((ext_vector_type(8)));
typedef float f32x4v __attribute__((ext_vector_type(4)));

__host__ __device__ inline void tf2x32(uint32_t k0, uint32_t k1,
                                       uint32_t x0, uint32_t x1,
                                       uint32_t &o0, uint32_t &o1)
{
    uint32_t ks2 = k0 ^ k1 ^ 0x1BD11BDAu;
    uint32_t v0 = x0 + k0, v1 = x1 + k1;
#define TFR(d) { v0 += v1; v1 = (v1 << (d)) | (v1 >> (32 - (d))); v1 ^= v0; }
    TFR(13) TFR(15) TFR(26) TFR(6)   v0 += k1;  v1 += ks2 + 1u;
    TFR(17) TFR(29) TFR(16) TFR(24)  v0 += ks2; v1 += k0 + 2u;
    TFR(13) TFR(15) TFR(26) TFR(6)   v0 += k0;  v1 += k1 + 3u;
    TFR(17) TFR(29) TFR(16) TFR(24)  v0 += k1;  v1 += ks2 + 4u;
    TFR(13) TFR(15) TFR(26) TFR(6)   v0 += ks2; v1 += k0 + 5u;
#undef TFR
    o0 = v0; o1 = v1;
}

__device__ inline uint16_t f32_to_bf16_rne(float f)
{
    uint32_t u = __float_as_uint(f);
    u += 0x7FFFu + ((u >> 16) & 1u);
    return (uint16_t)(u >> 16);
}
__device__ inline float bf16_to_f32(uint16_t h)
{
    return __uint_as_float(((uint32_t)h) << 16);
}

__device__ __forceinline__ void split_write(float4 v, uint16_t* __restrict__ H,
                                            uint16_t* __restrict__ L, size_t off)
{
    uint16_t b0 = f32_to_bf16_rne(v.x), b1 = f32_to_bf16_rne(v.y);
    uint16_t b2 = f32_to_bf16_rne(v.z), b3 = f32_to_bf16_rne(v.w);
    *(ushort4*)&H[off] = make_ushort4(b0, b1, b2, b3);
    *(ushort4*)&L[off] = make_ushort4(f32_to_bf16_rne(v.x - bf16_to_f32(b0)),
                                      f32_to_bf16_rne(v.y - bf16_to_f32(b1)),
                                      f32_to_bf16_rne(v.z - bf16_to_f32(b2)),
                                      f32_to_bf16_rne(v.w - bf16_to_f32(b3)));
}

// Fused prep + means + x-row pre-gather (r13, unchanged).
__global__ void means_prep_kernel(const int* __restrict__ ids, const int* __restrict__ adj,
                                  const float* __restrict__ feats,
                                  const float* __restrict__ Wx1, const float* __restrict__ Wn1,
                                  uint16_t* __restrict__ xh, uint16_t* __restrict__ xl,
                                  uint16_t* __restrict__ nh, uint16_t* __restrict__ nl,
                                  uint32_t s0a, uint32_t s0b, uint32_t s1a, uint32_t s1b,
                                  uint16_t* __restrict__ m1h, uint16_t* __restrict__ m1l,
                                  uint16_t* __restrict__ m0h, uint16_t* __restrict__ m0l,
                                  uint16_t* __restrict__ xrh, uint16_t* __restrict__ xrl,
                                  uint16_t* __restrict__ x0h, uint16_t* __restrict__ x0l,
                                  float4* __restrict__ m2z)
{
    const int tid = threadIdx.x;
    const int bid = blockIdx.x;

    if (bid < 384) {
        int t = bid * 256 + tid;
        if (t < 32768) {
            int k = (t & 16383) >> 7, n = t & 127;
            const float* W = (t < 16384) ? Wx1 : Wn1;
            uint16_t* H = (t < 16384) ? xh : nh;
            uint16_t* L = (t < 16384) ? xl : nl;
            float v = W[k * 128 + n];
            uint16_t h = f32_to_bf16_rne(v);
            uint16_t l = f32_to_bf16_rne(v - bf16_to_f32(h));
            H[n * 128 + k] = h;
            L[n * 128 + k] = l;
        } else {
            m2z[t - 32768] = make_float4(0.f, 0.f, 0.f, 0.f);
        }
    }

    const int v = (bid * 256 + tid) >> 6;
    const int lane = tid & 63;
    const int half = lane >> 5;
    const int h = lane & 31;

    if (v < 12800) {
        const int r = v * 2 + half;
        uint32_t h0, l0;
        tf2x32(s0a, s0b, 0u, (uint32_t)r, h0, l0);
        int s1idx = adj[(size_t)ids[r / 25] * 128u + ((h0 ^ l0) & 127u)];
        {
            float4 xv = *((const float4*)(feats + (size_t)s1idx * 128) + h);
            split_write(xv, xrh, xrl, (size_t)r * 128 + h * 4);
        }
        int idv = 0;
        if (h < 10) {
            uint32_t hh, ll;
            tf2x32(s1a, s1b, 0u, (uint32_t)(r * 10 + h), hh, ll);
            idv = adj[(size_t)s1idx * 128u + ((hh ^ ll) & 127u)];
        }
        float a0 = 0.f, a1 = 0.f, a2 = 0.f, a3 = 0.f;
#pragma unroll
        for (int t = 0; t < 10; ++t) {
            int id = __shfl(idv, (lane & 32) + t, 64);
            float4 vv = *((const float4*)(feats + (size_t)id * 128) + h);
            a0 += vv.x; a1 += vv.y; a2 += vv.z; a3 += vv.w;
        }
        float4 m; m.x = a0 * 0.1f; m.y = a1 * 0.1f; m.z = a2 * 0.1f; m.w = a3 * 0.1f;
        split_write(m, m1h, m1l, (size_t)r * 128 + h * 4);
    } else if (v < 13312) {
        const int r = (v - 12800) * 2 + half;
        int s = ids[r];
        {
            float4 xv = *((const float4*)(feats + (size_t)s * 128) + h);
            split_write(xv, x0h, x0l, (size_t)r * 128 + h * 4);
        }
        int idv = 0;
        if (h < 25) {
            uint32_t hh, ll;
            tf2x32(s0a, s0b, 0u, (uint32_t)(r * 25 + h), hh, ll);
            idv = adj[(size_t)s * 128u + ((hh ^ ll) & 127u)];
        }
        float a0 = 0.f, a1 = 0.f, a2 = 0.f, a3 = 0.f;
#pragma unroll
        for (int t = 0; t < 25; ++t) {
            int id = __shfl(idv, (lane & 32) + t, 64);
            float4 vv = *((const float4*)(feats + (size_t)id * 128) + h);
            a0 += vv.x; a1 += vv.y; a2 += vv.z; a3 += vv.w;
        }
        const float sc = 1.0f / 25.0f;
        float4 m; m.x = a0 * sc; m.y = a1 * sc; m.z = a2 * sc; m.w = a3 * sc;
        split_write(m, m0h, m0l, (size_t)r * 128 + h * 4);
    }
}

// Layer-1 GEMM (r13, unchanged).
__launch_bounds__(256)
__global__ void gemm_l1(const uint16_t* __restrict__ xrh, const uint16_t* __restrict__ xrl,
                        const uint16_t* __restrict__ m1h, const uint16_t* __restrict__ m1l,
                        const uint16_t* __restrict__ x0h, const uint16_t* __restrict__ x0l,
                        const uint16_t* __restrict__ m0h, const uint16_t* __restrict__ m0l,
                        const uint16_t* __restrict__ xh, const uint16_t* __restrict__ xl,
                        const uint16_t* __restrict__ nh, const uint16_t* __restrict__ nl,
                        float* __restrict__ m2, float* __restrict__ h10)
{
    __shared__ __align__(16) char smem[34816];
    uint16_t (*Ahi)[136] = reinterpret_cast<uint16_t(*)[136]>(smem);
    uint16_t (*Alo)[136] = reinterpret_cast<uint16_t(*)[136]>(smem + 17408);

    const int tid = threadIdx.x;
    const int vb = blockIdx.x;
    int z, bx;
    if (vb < 16)      { z = 3; bx = vb; }
    else if (vb < 32) { z = 2; bx = vb - 16; }
    else              { int q = vb - 32; z = q & 1; bx = q >> 1; }
    const int rb = bx * 64;
    const bool isX = (z == 0) || (z == 2);
    const uint16_t* WH = isX ? xh : nh;
    const uint16_t* WL = isX ? xl : nl;
    const int ccol0 = isX ? 0 : 128;
    const uint16_t* SH; const uint16_t* SL;
    switch (z) {
    case 0:  SH = xrh; SL = xrl; break;
    case 1:  SH = m1h; SL = m1l; break;
    case 2:  SH = x0h; SL = x0l; break;
    default: SH = m0h; SL = m0l; break;
    }

    const int lane = tid & 63;
    const int wv = tid >> 6;

#pragma unroll
    for (int i = 0; i < 4; ++i) {
        int s = tid + i * 256;
        int row = s >> 4, c8 = (s & 15) * 8;
        *(uint4*)&Ahi[row][c8] = *(const uint4*)(SH + (size_t)(rb + row) * 128 + c8);
        *(uint4*)&Alo[row][c8] = *(const uint4*)(SL + (size_t)(rb + row) * 128 + c8);
    }
    __syncthreads();

    const int wm = (wv >> 1) * 32;
    const int wn = (wv & 1) * 64;
    const int fr = lane & 15;
    const int kb = lane >> 4;

    f32x4v acc[2][4] = {};
#pragma unroll
    for (int ks = 0; ks < 4; ++ks) {
        const int kk = ks * 32 + kb * 8;
        bf16x8v aH[2], aL[2];
#pragma unroll
        for (int mi = 0; mi < 2; ++mi) {
            aH[mi] = *(const bf16x8v*)&Ahi[wm + mi * 16 + fr][kk];
            aL[mi] = *(const bf16x8v*)&Alo[wm + mi * 16 + fr][kk];
        }
#pragma unroll
        for (int ni = 0; ni < 4; ++ni) {
            size_t wrow = (size_t)(wn + ni * 16 + fr) * 128 + kk;
            bf16x8v bH = *(const bf16x8v*)(WH + wrow);
            bf16x8v bL = *(const bf16x8v*)(WL + wrow);
#pragma unroll
            for (int mi = 0; mi < 2; ++mi) {
                acc[mi][ni] = __builtin_amdgcn_mfma_f32_16x16x32_bf16(aH[mi], bH, acc[mi][ni], 0, 0, 0);
                acc[mi][ni] = __builtin_amdgcn_mfma_f32_16x16x32_bf16(aH[mi], bL, acc[mi][ni], 0, 0, 0);
                acc[mi][ni] = __builtin_amdgcn_mfma_f32_16x16x32_bf16(aL[mi], bH, acc[mi][ni], 0, 0, 0);
            }
        }
    }

    if (z < 2) {
        __syncthreads();
        float (*Red)[132] = reinterpret_cast<float(*)[132]>(smem);
#pragma unroll
        for (int mi = 0; mi < 2; ++mi)
#pragma unroll
            for (int ni = 0; ni < 4; ++ni) {
                int rl = wm + mi * 16 + kb * 4;
                int cl = wn + ni * 16 + fr;
#pragma unroll
                for (int r = 0; r < 4; ++r)
                    Red[rl + r][cl] = fmaxf(acc[mi][ni][r], 0.0f);
            }
        __syncthreads();
        int col = tid & 127;
        for (int gg = rb / 25 + (tid >> 7); gg * 25 < rb + 64; gg += 2) {
            int rs = max(gg * 25, rb), re = min(gg * 25 + 25, rb + 64);
            float s = 0.f;
            for (int r = rs; r < re; ++r) s += Red[r - rb][col];
            atomicAdd(&m2[(size_t)gg * 256 + ccol0 + col], s * (1.0f / 25.0f));
        }
    } else {
#pragma unroll
        for (int mi = 0; mi < 2; ++mi)
#pragma unroll
            for (int ni = 0; ni < 4; ++ni) {
                int orow = rb + wm + mi * 16 + kb * 4;
                int ocol = ccol0 + wn + ni * 16 + fr;
#pragma unroll
                for (int r = 0; r < 4; ++r)
                    h10[(size_t)(orow + r) * 256 + ocol] = fmaxf(acc[mi][ni][r], 0.0f);
            }
    }
}

// Tail (r4/r7 frozen).
__launch_bounds__(256)
__global__ void tail_kernel(const float* __restrict__ h10, const float* __restrict__ m2,
                            const float* __restrict__ Wx2, const float* __restrict__ Wn2,
                            const float* __restrict__ fcw, const float* __restrict__ fcb,
                            float* __restrict__ out)
{
    __shared__ float X[4][260];
    __shared__ float M[4][260];
    __shared__ float H[4][260];
    const int tid = threadIdx.x;
    const int r0 = blockIdx.x * 4;

    {
        int r = tid >> 6, q = tid & 63;
        *(float4*)&X[r][q * 4] = *((const float4*)(h10 + (size_t)(r0 + r) * 256) + q);
        *(float4*)&M[r][q * 4] = *((const float4*)(m2 + (size_t)(r0 + r) * 256) + q);
    }
    __syncthreads();

    {
        const float* W = (tid < 128) ? Wx2 : Wn2;
        const float (*S)[260] = (tid < 128) ? X : M;
        int c = tid & 127;
        float acc0 = 0.f, acc1 = 0.f, acc2 = 0.f, acc3 = 0.f;
        for (int k4 = 0; k4 < 256; k4 += 4) {
            float4 s0 = *(const float4*)&S[0][k4];
            float4 s1 = *(const float4*)&S[1][k4];
            float4 s2 = *(const float4*)&S[2][k4];
            float4 s3 = *(const float4*)&S[3][k4];
            float w0 = W[(size_t)(k4 + 0) * 128 + c];
            float w1 = W[(size_t)(k4 + 1) * 128 + c];
            float w2 = W[(size_t)(k4 + 2) * 128 + c];
            float w3 = W[(size_t)(k4 + 3) * 128 + c];
            acc0 = fmaf(s0.x, w0, fmaf(s0.y, w1, fmaf(s0.z, w2, fmaf(s0.w, w3, acc0))));
            acc1 = fmaf(s1.x, w0, fmaf(s1.y, w1, fmaf(s1.z, w2, fmaf(s1.w, w3, acc1))));
            acc2 = fmaf(s2.x, w0, fmaf(s2.y, w1, fmaf(s2.z, w2, fmaf(s2.w, w3, acc2))));
            acc3 = fmaf(s3.x, w0, fmaf(s3.y, w1, fmaf(s3.z, w2, fmaf(s3.w, w3, acc3))));
        }
        H[0][tid] = acc0; H[1][tid] = acc1; H[2][tid] = acc2; H[3][tid] = acc3;
    }
    __syncthreads();

    const int w = tid >> 6, lane = tid & 63;
    float4 hv = *((const float4*)&H[w][0] + lane);
    float ss = hv.x * hv.x + hv.y * hv.y + hv.z * hv.z + hv.w * hv.w;
#pragma unroll
    for (int o = 32; o > 0; o >>= 1) ss += __shfl_xor(ss, o, 64);
    float scale = 1.0f / fmaxf(sqrtf(ss), 1e-12f);

    float acc = 0.f;
    for (int k4 = 0; k4 < 256; k4 += 4) {
        float4 h4 = *(const float4*)&H[w][k4];
        acc = fmaf(h4.x, fcw[(size_t)(k4 + 0) * 64 + lane],
              fmaf(h4.y, fcw[(size_t)(k4 + 1) * 64 + lane],
              fmaf(h4.z, fcw[(size_t)(k4 + 2) * 64 + lane],
              fmaf(h4.w, fcw[(size_t)(k4 + 3) * 64 + lane], acc))));
    }
    out[(size_t)(r0 + w) * 64 + lane] = acc * scale + fcb[lane];
}

extern "C" void kernel_launch(void* const* d_in, const int* in_sizes, int n_in,
                              void* d_out, int out_size, void* d_ws, size_t ws_size,
                              hipStream_t stream)
{
    const int*   ids   = (const int*)d_in[0];
    const float* feats = (const float*)d_in[1];
    const int*   adj   = (const int*)d_in[2];
    const float* W_x1  = (const float*)d_in[3];
    const float* W_n1  = (const float*)d_in[4];
    const float* W_x2  = (const float*)d_in[5];
    const float* W_n2  = (const float*)d_in[6];
    const float* fc_w  = (const float*)d_in[7];
    const float* fc_b  = (const float*)d_in[8];
    float* out = (float*)d_out;

    char* ws = (char*)d_ws;
    uint16_t* m1h = (uint16_t*)(ws + 0);
    uint16_t* m1l = (uint16_t*)(ws + 6553600);
    uint16_t* xrh = (uint16_t*)(ws + 13107200);
    uint16_t* xrl = (uint16_t*)(ws + 19660800);
    uint16_t* m0h = (uint16_t*)(ws + 26214400);
    uint16_t* m0l = (uint16_t*)(ws + 26476544);
    uint16_t* x0h = (uint16_t*)(ws + 26738688);
    uint16_t* x0l = (uint16_t*)(ws + 27000832);
    float*    h10 = (float*)(ws + 27262976);
    float*    m2  = (float*)(ws + 28311552);
    uint16_t* xh  = (uint16_t*)(ws + 29360128);
    uint16_t* xl  = (uint16_t*)(ws + 29392896);
    uint16_t* nh  = (uint16_t*)(ws + 29425664);
    uint16_t* nl  = (uint16_t*)(ws + 29458432);
    float*    m2d = (float*)(ws + 29491200);   // dummy outputs for diagnostic reps
    float*    h10d= (float*)(ws + 30539776);   // end 31,588,352 B

    uint32_t f0a, f0b, f1a, f1b, s0a, s0b, s1a, s1b;
    tf2x32(0u, 42u, 0u, 0u, f0a, f0b);
    tf2x32(0u, 42u, 0u, 1u, f1a, f1b);
    tf2x32(f0a, f0b, 0u, 1u, s0a, s0b);
    tf2x32(f1a, f1b, 0u, 1u, s1a, s1b);

    means_prep_kernel<<<3328, 256, 0, stream>>>(ids, adj, feats, W_x1, W_n1,
                                                xh, xl, nh, nl,
                                                s0a, s0b, s1a, s1b,
                                                m1h, m1l, m0h, m0l,
                                                xrh, xrl, x0h, x0l,
                                                (float4*)m2);
    // DIAGNOSTIC: two dummy gemm launches (outputs never read), then real one.
    gemm_l1<<<832, 256, 0, stream>>>(xrh, xrl, m1h, m1l, x0h, x0l, m0h, m0l,
                                     xh, xl, nh, nl, m2d, h10d);
    gemm_l1<<<832, 256, 0, stream>>>(xrh, xrl, m1h, m1l, x0h, x0l, m0h, m0l,
                                     xh, xl, nh, nl, m2d, h10d);
    gemm_l1<<<832, 256, 0, stream>>>(xrh, xrl, m1h, m1l, x0h, x0l, m0h, m0l,
                                     xh, xl, nh, nl, m2, h10);
    tail_kernel<<<256, 256, 0, stream>>>(h10, m2, W_x2, W_n2, fc_w, fc_b, out);
}

// Round 15
// 68.019 us; speedup vs baseline: 1.6126x; 1.6126x over previous
//
#include <hip/hip_runtime.h>
#include <stdint.h>
#include <stddef.h>

// ---------------------------------------------------------------------------
// GraphSAGE supervised forward (B=1024, D=HID=128, fanout 25/10, classes 64)
// Round 15: fused gather+GEMM with BM=16 tiles (8.7KB LDS, 8 blocks/CU).
// 1600 heavy z1 blocks (vs r12's 400) -> gather phase runs at high occupancy.
// 3 launches: prologue -> fused gemm (3328 blocks) -> tail.
// ---------------------------------------------------------------------------

typedef short bf16x8v __attribute__((ext_vector_type(8)));
typedef float f32x4v __attribute__((ext_vector_type(4)));

__host__ __device__ inline void tf2x32(uint32_t k0, uint32_t k1,
                                       uint32_t x0, uint32_t x1,
                                       uint32_t &o0, uint32_t &o1)
{
    uint32_t ks2 = k0 ^ k1 ^ 0x1BD11BDAu;
    uint32_t v0 = x0 + k0, v1 = x1 + k1;
#define TFR(d) { v0 += v1; v1 = (v1 << (d)) | (v1 >> (32 - (d))); v1 ^= v0; }
    TFR(13) TFR(15) TFR(26) TFR(6)   v0 += k1;  v1 += ks2 + 1u;
    TFR(17) TFR(29) TFR(16) TFR(24)  v0 += ks2; v1 += k0 + 2u;
    TFR(13) TFR(15) TFR(26) TFR(6)   v0 += k0;  v1 += k1 + 3u;
    TFR(17) TFR(29) TFR(16) TFR(24)  v0 += k1;  v1 += ks2 + 4u;
    TFR(13) TFR(15) TFR(26) TFR(6)   v0 += ks2; v1 += k0 + 5u;
#undef TFR
    o0 = v0; o1 = v1;
}

__device__ inline uint16_t f32_to_bf16_rne(float f)
{
    uint32_t u = __float_as_uint(f);
    u += 0x7FFFu + ((u >> 16) & 1u);
    return (uint16_t)(u >> 16);
}
__device__ inline float bf16_to_f32(uint16_t h)
{
    return __uint_as_float(((uint32_t)h) << 16);
}

// Prologue, one item per thread (r8/r12-validated):
//   [0,32768) W split-transpose; [32768,98304) zero m2;
//   [98304,123904) hop-1 -> ids1; [123904,379904) hop-2 -> ids2.
__global__ void prologue_kernel(const int* __restrict__ ids, const int* __restrict__ adj,
                                const float* __restrict__ Wx1, const float* __restrict__ Wn1,
                                uint16_t* __restrict__ xh, uint16_t* __restrict__ xl,
                                uint16_t* __restrict__ nh, uint16_t* __restrict__ nl,
                                uint32_t s0a, uint32_t s0b, uint32_t s1a, uint32_t s1b,
                                int* __restrict__ ids1, int* __restrict__ ids2,
                                float4* __restrict__ m2z)
{
    int t = blockIdx.x * 256 + threadIdx.x;
    if (t < 32768) {
        int k = (t & 16383) >> 7, n = t & 127;
        const float* W = (t < 16384) ? Wx1 : Wn1;
        uint16_t* H = (t < 16384) ? xh : nh;
        uint16_t* L = (t < 16384) ? xl : nl;
        float v = W[k * 128 + n];
        uint16_t h = f32_to_bf16_rne(v);
        uint16_t l = f32_to_bf16_rne(v - bf16_to_f32(h));
        H[n * 128 + k] = h;
        L[n * 128 + k] = l;
    } else if (t < 98304) {
        m2z[t - 32768] = make_float4(0.f, 0.f, 0.f, 0.f);
    } else if (t < 123904) {
        int j = t - 98304;
        uint32_t h, l;
        tf2x32(s0a, s0b, 0u, (uint32_t)j, h, l);
        ids1[j] = adj[(size_t)ids[j / 25] * 128u + ((h ^ l) & 127u)];
    } else if (t < 379904) {
        int j = t - 123904;
        uint32_t h0, l0;
        tf2x32(s0a, s0b, 0u, (uint32_t)(j / 10), h0, l0);
        int a1 = adj[(size_t)ids[j / 250] * 128u + ((h0 ^ l0) & 127u)];
        uint32_t h1, l1;
        tf2x32(s1a, s1b, 0u, (uint32_t)j, h1, l1);
        ids2[j] = adj[(size_t)a1 * 128u + ((h1 ^ l1) & 127u)];
    }
}

// Fused gather+GEMM: BM=16, BN=128 (full), K=128, split-bf16 MFMA.
// vb<1600: z1 (mean10 inline, HEAVY, first); vb<3200: z0 (gather ids1);
// vb<3264: z2 (gather ids); else z3 (mean25 inline).
// z0/z1 -> mean25 epilogue atomicAdd m2; z2/z3 -> relu write h10.
__launch_bounds__(256)
__global__ void gemm_fused(const float* __restrict__ feats, const int* __restrict__ ids,
                           const int* __restrict__ ids1, const int* __restrict__ ids2,
                           const uint16_t* __restrict__ xh, const uint16_t* __restrict__ xl,
                           const uint16_t* __restrict__ nh, const uint16_t* __restrict__ nl,
                           float* __restrict__ m2, float* __restrict__ h10)
{
    __shared__ __align__(16) char smem[8704];
    uint16_t (*Ahi)[136] = reinterpret_cast<uint16_t(*)[136]>(smem);
    uint16_t (*Alo)[136] = reinterpret_cast<uint16_t(*)[136]>(smem + 4352);

    const int tid = threadIdx.x;
    const int vb = blockIdx.x;
    int z, bx;
    if (vb < 1600)      { z = 1; bx = vb; }
    else if (vb < 3200) { z = 0; bx = vb - 1600; }
    else if (vb < 3264) { z = 2; bx = vb - 3200; }
    else                { z = 3; bx = vb - 3264; }
    const int rb = bx * 16;
    const bool isX = (z == 0) || (z == 2);
    const uint16_t* WH = isX ? xh : nh;
    const uint16_t* WL = isX ? xl : nl;
    const int ccol0 = isX ? 0 : 128;

    const int lane = tid & 63;
    const int wv = tid >> 6;

    // ---- stage A (16 rows x 128 k, bf16 hi/lo) ----
    if (isX) {                               // row gather + split: 2 chunks/thread
        const int* g = (z == 0) ? ids1 : ids;
#pragma unroll
        for (int i = 0; i < 2; ++i) {
            int s = tid + i * 256;
            int row = s >> 5, f4 = s & 31, k0 = f4 * 4;
            size_t arow = (size_t)g[rb + row];
            float4 v = *(const float4*)(feats + arow * 128 + k0);
            uint16_t h0 = f32_to_bf16_rne(v.x), h1 = f32_to_bf16_rne(v.y);
            uint16_t h2 = f32_to_bf16_rne(v.z), h3 = f32_to_bf16_rne(v.w);
            *(ushort4*)&Ahi[row][k0] = make_ushort4(h0, h1, h2, h3);
            *(ushort4*)&Alo[row][k0] = make_ushort4(f32_to_bf16_rne(v.x - bf16_to_f32(h0)),
                                                    f32_to_bf16_rne(v.y - bf16_to_f32(h1)),
                                                    f32_to_bf16_rne(v.z - bf16_to_f32(h2)),
                                                    f32_to_bf16_rne(v.w - bf16_to_f32(h3)));
        }
    } else {
        // inline mean: half-wave (32 lanes) owns 2 rows; idv hoisted.
        const int h = lane & 31;
        const int hw = tid >> 5;             // 0..7
        const int FAN = (z == 1) ? 10 : 25;
        const int* src = (z == 1) ? ids2 : ids1;
        const float sc = (z == 1) ? 0.1f : (1.0f / 25.0f);
        int idv[2];
#pragma unroll
        for (int j = 0; j < 2; ++j) {
            int r = rb + hw * 2 + j;
            idv[j] = (h < FAN) ? src[(size_t)r * FAN + h] : 0;
        }
#pragma unroll
        for (int j = 0; j < 2; ++j) {
            float a0 = 0.f, a1 = 0.f, a2 = 0.f, a3 = 0.f;
            if (z == 1) {
#pragma unroll
                for (int t = 0; t < 10; ++t) {
                    int id = __shfl(idv[j], (lane & 32) + t, 64);
                    float4 vv = *((const float4*)(feats + (size_t)id * 128) + h);
                    a0 += vv.x; a1 += vv.y; a2 += vv.z; a3 += vv.w;
                }
            } else {
#pragma unroll
                for (int t = 0; t < 25; ++t) {
                    int id = __shfl(idv[j], (lane & 32) + t, 64);
                    float4 vv = *((const float4*)(feats + (size_t)id * 128) + h);
                    a0 += vv.x; a1 += vv.y; a2 += vv.z; a3 += vv.w;
                }
            }
            a0 *= sc; a1 *= sc; a2 *= sc; a3 *= sc;
            uint16_t b0 = f32_to_bf16_rne(a0), b1 = f32_to_bf16_rne(a1);
            uint16_t b2 = f32_to_bf16_rne(a2), b3 = f32_to_bf16_rne(a3);
            int row = hw * 2 + j;
            *(ushort4*)&Ahi[row][h * 4] = make_ushort4(b0, b1, b2, b3);
            *(ushort4*)&Alo[row][h * 4] =
                make_ushort4(f32_to_bf16_rne(a0 - bf16_to_f32(b0)),
                             f32_to_bf16_rne(a1 - bf16_to_f32(b1)),
                             f32_to_bf16_rne(a2 - bf16_to_f32(b2)),
                             f32_to_bf16_rne(a3 - bf16_to_f32(b3)));
        }
    }
    __syncthreads();

    // ---- MFMA: 4 waves, each 16(M) x 32(N); B direct from global ----
    const int wn = wv * 32;
    const int fr = lane & 15;
    const int kb = lane >> 4;

    f32x4v acc[2] = {};
#pragma unroll
    for (int ks = 0; ks < 4; ++ks) {
        const int kk = ks * 32 + kb * 8;
        bf16x8v aH = *(const bf16x8v*)&Ahi[fr][kk];
        bf16x8v aL = *(const bf16x8v*)&Alo[fr][kk];
#pragma unroll
        for (int ni = 0; ni < 2; ++ni) {
            size_t wrow = (size_t)(wn + ni * 16 + fr) * 128 + kk;
            bf16x8v bH = *(const bf16x8v*)(WH + wrow);
            bf16x8v bL = *(const bf16x8v*)(WL + wrow);
            acc[ni] = __builtin_amdgcn_mfma_f32_16x16x32_bf16(aH, bH, acc[ni], 0, 0, 0);
            acc[ni] = __builtin_amdgcn_mfma_f32_16x16x32_bf16(aH, bL, acc[ni], 0, 0, 0);
            acc[ni] = __builtin_amdgcn_mfma_f32_16x16x32_bf16(aL, bH, acc[ni], 0, 0, 0);
        }
    }

    // C/D layout: col = fr, row = kb*4 + reg.
    if (z < 2) {
        __syncthreads();
        float (*Red)[132] = reinterpret_cast<float(*)[132]>(smem);   // 16x132x4 = 8448 B
#pragma unroll
        for (int ni = 0; ni < 2; ++ni)
#pragma unroll
            for (int r = 0; r < 4; ++r)
                Red[kb * 4 + r][wn + ni * 16 + fr] = fmaxf(acc[ni][r], 0.0f);
        __syncthreads();
        int col = tid & 127;
        for (int gg = rb / 25 + (tid >> 7); gg * 25 < rb + 16; gg += 2) {
            int rs = max(gg * 25, rb), re = min(gg * 25 + 25, rb + 16);
            float s = 0.f;
            for (int r = rs; r < re; ++r) s += Red[r - rb][col];
            atomicAdd(&m2[(size_t)gg * 256 + ccol0 + col], s * (1.0f / 25.0f));
        }
    } else {
#pragma unroll
        for (int ni = 0; ni < 2; ++ni) {
            int ocol = ccol0 + wn + ni * 16 + fr;
#pragma unroll
            for (int r = 0; r < 4; ++r)
                h10[(size_t)(rb + kb * 4 + r) * 256 + ocol] = fmaxf(acc[ni][r], 0.0f);
        }
    }
}

// Tail: layer-2 GEMM (K=256) + row-normalize + FC (r4/r7 frozen).
__launch_bounds__(256)
__global__ void tail_kernel(const float* __restrict__ h10, const float* __restrict__ m2,
                            const float* __restrict__ Wx2, const float* __restrict__ Wn2,
                            const float* __restrict__ fcw, const float* __restrict__ fcb,
                            float* __restrict__ out)
{
    __shared__ float X[4][260];
    __shared__ float M[4][260];
    __shared__ float H[4][260];
    const int tid = threadIdx.x;
    const int r0 = blockIdx.x * 4;

    {
        int r = tid >> 6, q = tid & 63;
        *(float4*)&X[r][q * 4] = *((const float4*)(h10 + (size_t)(r0 + r) * 256) + q);
        *(float4*)&M[r][q * 4] = *((const float4*)(m2 + (size_t)(r0 + r) * 256) + q);
    }
    __syncthreads();

    {
        const float* W = (tid < 128) ? Wx2 : Wn2;
        const float (*S)[260] = (tid < 128) ? X : M;
        int c = tid & 127;
        float acc0 = 0.f, acc1 = 0.f, acc2 = 0.f, acc3 = 0.f;
        for (int k4 = 0; k4 < 256; k4 += 4) {
            float4 s0 = *(const float4*)&S[0][k4];
            float4 s1 = *(const float4*)&S[1][k4];
            float4 s2 = *(const float4*)&S[2][k4];
            float4 s3 = *(const float4*)&S[3][k4];
            float w0 = W[(size_t)(k4 + 0) * 128 + c];
            float w1 = W[(size_t)(k4 + 1) * 128 + c];
            float w2 = W[(size_t)(k4 + 2) * 128 + c];
            float w3 = W[(size_t)(k4 + 3) * 128 + c];
            acc0 = fmaf(s0.x, w0, fmaf(s0.y, w1, fmaf(s0.z, w2, fmaf(s0.w, w3, acc0))));
            acc1 = fmaf(s1.x, w0, fmaf(s1.y, w1, fmaf(s1.z, w2, fmaf(s1.w, w3, acc1))));
            acc2 = fmaf(s2.x, w0, fmaf(s2.y, w1, fmaf(s2.z, w2, fmaf(s2.w, w3, acc2))));
            acc3 = fmaf(s3.x, w0, fmaf(s3.y, w1, fmaf(s3.z, w2, fmaf(s3.w, w3, acc3))));
        }
        H[0][tid] = acc0; H[1][tid] = acc1; H[2][tid] = acc2; H[3][tid] = acc3;
    }
    __syncthreads();

    const int w = tid >> 6, lane = tid & 63;
    float4 hv = *((const float4*)&H[w][0] + lane);
    float ss = hv.x * hv.x + hv.y * hv.y + hv.z * hv.z + hv.w * hv.w;
#pragma unroll
    for (int o = 32; o > 0; o >>= 1) ss += __shfl_xor(ss, o, 64);
    float scale = 1.0f / fmaxf(sqrtf(ss), 1e-12f);

    float acc = 0.f;
    for (int k4 = 0; k4 < 256; k4 += 4) {
        float4 h4 = *(const float4*)&H[w][k4];
        acc = fmaf(h4.x, fcw[(size_t)(k4 + 0) * 64 + lane],
              fmaf(h4.y, fcw[(size_t)(k4 + 1) * 64 + lane],
              fmaf(h4.z, fcw[(size_t)(k4 + 2) * 64 + lane],
              fmaf(h4.w, fcw[(size_t)(k4 + 3) * 64 + lane], acc))));
    }
    out[(size_t)(r0 + w) * 64 + lane] = acc * scale + fcb[lane];
}

extern "C" void kernel_launch(void* const* d_in, const int* in_sizes, int n_in,
                              void* d_out, int out_size, void* d_ws, size_t ws_size,
                              hipStream_t stream)
{
    const int*   ids   = (const int*)d_in[0];
    const float* feats = (const float*)d_in[1];
    const int*   adj   = (const int*)d_in[2];
    const float* W_x1  = (const float*)d_in[3];
    const float* W_n1  = (const float*)d_in[4];
    const float* W_x2  = (const float*)d_in[5];
    const float* W_n2  = (const float*)d_in[6];
    const float* fc_w  = (const float*)d_in[7];
    const float* fc_b  = (const float*)d_in[8];
    float* out = (float*)d_out;

    char* ws = (char*)d_ws;
    int*      ids1 = (int*)(ws + 0);            // 25600 x 4
    int*      ids2 = (int*)(ws + 102400);       // 256000 x 4
    float*    h10  = (float*)(ws + 1126400);    // 1024 x 256 f32
    float*    m2   = (float*)(ws + 2174976);    // 1024 x 256 f32 (atomics)
    uint16_t* xh   = (uint16_t*)(ws + 3223552); // W splits, 32,768 each
    uint16_t* xl   = (uint16_t*)(ws + 3256320);
    uint16_t* nh   = (uint16_t*)(ws + 3289088);
    uint16_t* nl   = (uint16_t*)(ws + 3321856); // end 3,354,624 B

    // JAX PRNG key derivation (threefry2x32, partitionable foldlike):
    uint32_t f0a, f0b, f1a, f1b, s0a, s0b, s1a, s1b;
    tf2x32(0u, 42u, 0u, 0u, f0a, f0b);
    tf2x32(0u, 42u, 0u, 1u, f1a, f1b);
    tf2x32(f0a, f0b, 0u, 1u, s0a, s0b);
    tf2x32(f1a, f1b, 0u, 1u, s1a, s1b);

    // 1) prologue: W splits + ids1 + ids2 + zero m2
    prologue_kernel<<<1484, 256, 0, stream>>>(ids, adj, W_x1, W_n1,
                                              xh, xl, nh, nl,
                                              s0a, s0b, s1a, s1b,
                                              ids1, ids2, (float4*)m2);
    // 2) fused gather+GEMM, BM=16: 1600 heavy z1 blocks first
    gemm_fused<<<3328, 256, 0, stream>>>(feats, ids, ids1, ids2,
                                         xh, xl, nh, nl, m2, h10);
    // 3) tail: layer-2 GEMM + normalize + FC
    tail_kernel<<<256, 256, 0, stream>>>(h10, m2, W_x2, W_n2, fc_w, fc_b, out);
}

// Round 17
// 63.737 us; speedup vs baseline: 1.7209x; 1.0672x over previous
//
#include <hip/hip_runtime.h>
#include <stdint.h>
#include <stddef.h>

// ---------------------------------------------------------------------------
// GraphSAGE supervised forward (B=1024, D=HID=128, fanout 25/10, classes 64)
// Round 17: r16 fixed — isX staging loop now 4 iterations (2048 chunks for
// the 64x128 tile; r16 staged only half -> NaN). BM=64, 512-thread blocks.
// 3 launches: prologue -> fused gemm (832x512) -> tail.
// ---------------------------------------------------------------------------

typedef short bf16x8v __attribute__((ext_vector_type(8)));
typedef float f32x4v __attribute__((ext_vector_type(4)));

__host__ __device__ inline void tf2x32(uint32_t k0, uint32_t k1,
                                       uint32_t x0, uint32_t x1,
                                       uint32_t &o0, uint32_t &o1)
{
    uint32_t ks2 = k0 ^ k1 ^ 0x1BD11BDAu;
    uint32_t v0 = x0 + k0, v1 = x1 + k1;
#define TFR(d) { v0 += v1; v1 = (v1 << (d)) | (v1 >> (32 - (d))); v1 ^= v0; }
    TFR(13) TFR(15) TFR(26) TFR(6)   v0 += k1;  v1 += ks2 + 1u;
    TFR(17) TFR(29) TFR(16) TFR(24)  v0 += ks2; v1 += k0 + 2u;
    TFR(13) TFR(15) TFR(26) TFR(6)   v0 += k0;  v1 += k1 + 3u;
    TFR(17) TFR(29) TFR(16) TFR(24)  v0 += k1;  v1 += ks2 + 4u;
    TFR(13) TFR(15) TFR(26) TFR(6)   v0 += ks2; v1 += k0 + 5u;
#undef TFR
    o0 = v0; o1 = v1;
}

__device__ inline uint16_t f32_to_bf16_rne(float f)
{
    uint32_t u = __float_as_uint(f);
    u += 0x7FFFu + ((u >> 16) & 1u);
    return (uint16_t)(u >> 16);
}
__device__ inline float bf16_to_f32(uint16_t h)
{
    return __uint_as_float(((uint32_t)h) << 16);
}

// Prologue, one item per thread (r8/r12-validated):
//   [0,32768) W split-transpose; [32768,98304) zero m2;
//   [98304,123904) hop-1 -> ids1; [123904,379904) hop-2 -> ids2.
__global__ void prologue_kernel(const int* __restrict__ ids, const int* __restrict__ adj,
                                const float* __restrict__ Wx1, const float* __restrict__ Wn1,
                                uint16_t* __restrict__ xh, uint16_t* __restrict__ xl,
                                uint16_t* __restrict__ nh, uint16_t* __restrict__ nl,
                                uint32_t s0a, uint32_t s0b, uint32_t s1a, uint32_t s1b,
                                int* __restrict__ ids1, int* __restrict__ ids2,
                                float4* __restrict__ m2z)
{
    int t = blockIdx.x * 256 + threadIdx.x;
    if (t < 32768) {
        int k = (t & 16383) >> 7, n = t & 127;
        const float* W = (t < 16384) ? Wx1 : Wn1;
        uint16_t* H = (t < 16384) ? xh : nh;
        uint16_t* L = (t < 16384) ? xl : nl;
        float v = W[k * 128 + n];
        uint16_t h = f32_to_bf16_rne(v);
        uint16_t l = f32_to_bf16_rne(v - bf16_to_f32(h));
        H[n * 128 + k] = h;
        L[n * 128 + k] = l;
    } else if (t < 98304) {
        m2z[t - 32768] = make_float4(0.f, 0.f, 0.f, 0.f);
    } else if (t < 123904) {
        int j = t - 98304;
        uint32_t h, l;
        tf2x32(s0a, s0b, 0u, (uint32_t)j, h, l);
        ids1[j] = adj[(size_t)ids[j / 25] * 128u + ((h ^ l) & 127u)];
    } else if (t < 379904) {
        int j = t - 123904;
        uint32_t h0, l0;
        tf2x32(s0a, s0b, 0u, (uint32_t)(j / 10), h0, l0);
        int a1 = adj[(size_t)ids[j / 250] * 128u + ((h0 ^ l0) & 127u)];
        uint32_t h1, l1;
        tf2x32(s1a, s1b, 0u, (uint32_t)j, h1, l1);
        ids2[j] = adj[(size_t)a1 * 128u + ((h1 ^ l1) & 127u)];
    }
}

// Fused gather+GEMM: BM=64, BN=128, K=128, split-bf16 MFMA, 512 thr (8 waves).
// vb<400: z1 (mean10 inline, heavy, first); vb<416: z3 (mean25 inline);
// vb<816: z0 (gather ids1); else z2 (gather ids).
// z0/z1 -> mean25 epilogue atomicAdd m2; z2/z3 -> relu write h10.
__launch_bounds__(512)
__global__ void gemm_fused(const float* __restrict__ feats, const int* __restrict__ ids,
                           const int* __restrict__ ids1, const int* __restrict__ ids2,
                           const uint16_t* __restrict__ xh, const uint16_t* __restrict__ xl,
                           const uint16_t* __restrict__ nh, const uint16_t* __restrict__ nl,
                           float* __restrict__ m2, float* __restrict__ h10)
{
    __shared__ __align__(16) char smem[34816];
    uint16_t (*Ahi)[136] = reinterpret_cast<uint16_t(*)[136]>(smem);
    uint16_t (*Alo)[136] = reinterpret_cast<uint16_t(*)[136]>(smem + 17408);

    const int tid = threadIdx.x;
    const int vb = blockIdx.x;
    int z, bx;
    if (vb < 400)      { z = 1; bx = vb; }
    else if (vb < 416) { z = 3; bx = vb - 400; }
    else if (vb < 816) { z = 0; bx = vb - 416; }
    else               { z = 2; bx = vb - 816; }
    const int rb = bx * 64;
    const bool isX = (z == 0) || (z == 2);
    const uint16_t* WH = isX ? xh : nh;
    const uint16_t* WL = isX ? xl : nl;
    const int ccol0 = isX ? 0 : 128;

    const int lane = tid & 63;
    const int wv = tid >> 6;            // 0..7

    // ---- stage A (64 rows x 128 k = 2048 float4 chunks, bf16 hi/lo) ----
    if (isX) {                          // row gather + split: 4 chunks/thread
        const int* g = (z == 0) ? ids1 : ids;
#pragma unroll
        for (int i = 0; i < 4; ++i) {
            int s = tid + i * 512;      // 0..2047
            int row = s >> 5, f4 = s & 31, k0 = f4 * 4;
            size_t arow = (size_t)g[rb + row];
            float4 v = *(const float4*)(feats + arow * 128 + k0);
            uint16_t h0 = f32_to_bf16_rne(v.x), h1 = f32_to_bf16_rne(v.y);
            uint16_t h2 = f32_to_bf16_rne(v.z), h3 = f32_to_bf16_rne(v.w);
            *(ushort4*)&Ahi[row][k0] = make_ushort4(h0, h1, h2, h3);
            *(ushort4*)&Alo[row][k0] = make_ushort4(f32_to_bf16_rne(v.x - bf16_to_f32(h0)),
                                                    f32_to_bf16_rne(v.y - bf16_to_f32(h1)),
                                                    f32_to_bf16_rne(v.z - bf16_to_f32(h2)),
                                                    f32_to_bf16_rne(v.w - bf16_to_f32(h3)));
        }
    } else {
        // inline mean: 16 half-waves, each owns 4 rows; idv hoisted.
        const int h = lane & 31;
        const int hw = tid >> 5;        // 0..15
        const int FAN = (z == 1) ? 10 : 25;
        const int* src = (z == 1) ? ids2 : ids1;
        const float sc = (z == 1) ? 0.1f : (1.0f / 25.0f);
        int idv[4];
#pragma unroll
        for (int j = 0; j < 4; ++j) {
            int r = rb + hw * 4 + j;
            idv[j] = (h < FAN) ? src[(size_t)r * FAN + h] : 0;
        }
#pragma unroll
        for (int j = 0; j < 4; ++j) {
            float a0 = 0.f, a1 = 0.f, a2 = 0.f, a3 = 0.f;
            if (z == 1) {
#pragma unroll
                for (int t = 0; t < 10; ++t) {
                    int id = __shfl(idv[j], (lane & 32) + t, 64);
                    float4 vv = *((const float4*)(feats + (size_t)id * 128) + h);
                    a0 += vv.x; a1 += vv.y; a2 += vv.z; a3 += vv.w;
                }
            } else {
#pragma unroll
                for (int t = 0; t < 25; ++t) {
                    int id = __shfl(idv[j], (lane & 32) + t, 64);
                    float4 vv = *((const float4*)(feats + (size_t)id * 128) + h);
                    a0 += vv.x; a1 += vv.y; a2 += vv.z; a3 += vv.w;
                }
            }
            a0 *= sc; a1 *= sc; a2 *= sc; a3 *= sc;
            uint16_t b0 = f32_to_bf16_rne(a0), b1 = f32_to_bf16_rne(a1);
            uint16_t b2 = f32_to_bf16_rne(a2), b3 = f32_to_bf16_rne(a3);
            int row = hw * 4 + j;
            *(ushort4*)&Ahi[row][h * 4] = make_ushort4(b0, b1, b2, b3);
            *(ushort4*)&Alo[row][h * 4] =
                make_ushort4(f32_to_bf16_rne(a0 - bf16_to_f32(b0)),
                             f32_to_bf16_rne(a1 - bf16_to_f32(b1)),
                             f32_to_bf16_rne(a2 - bf16_to_f32(b2)),
                             f32_to_bf16_rne(a3 - bf16_to_f32(b3)));
        }
    }
    __syncthreads();

    // ---- MFMA: 8 waves in 2x4 grid; each wave 32(M) x 32(N) ----
    const int wm = (wv >> 2) * 32;
    const int wn = (wv & 3) * 32;
    const int fr = lane & 15;
    const int kb = lane >> 4;

    f32x4v acc[2][2] = {};
#pragma unroll
    for (int ks = 0; ks < 4; ++ks) {
        const int kk = ks * 32 + kb * 8;
        bf16x8v aH[2], aL[2];
#pragma unroll
        for (int mi = 0; mi < 2; ++mi) {
            aH[mi] = *(const bf16x8v*)&Ahi[wm + mi * 16 + fr][kk];
            aL[mi] = *(const bf16x8v*)&Alo[wm + mi * 16 + fr][kk];
        }
#pragma unroll
        for (int ni = 0; ni < 2; ++ni) {
            size_t wrow = (size_t)(wn + ni * 16 + fr) * 128 + kk;
            bf16x8v bH = *(const bf16x8v*)(WH + wrow);
            bf16x8v bL = *(const bf16x8v*)(WL + wrow);
#pragma unroll
            for (int mi = 0; mi < 2; ++mi) {
                acc[mi][ni] = __builtin_amdgcn_mfma_f32_16x16x32_bf16(aH[mi], bH, acc[mi][ni], 0, 0, 0);
                acc[mi][ni] = __builtin_amdgcn_mfma_f32_16x16x32_bf16(aH[mi], bL, acc[mi][ni], 0, 0, 0);
                acc[mi][ni] = __builtin_amdgcn_mfma_f32_16x16x32_bf16(aL[mi], bH, acc[mi][ni], 0, 0, 0);
            }
        }
    }

    // C/D layout: col = fr, row = kb*4 + reg.
    if (z < 2) {
        __syncthreads();
        float (*Red)[132] = reinterpret_cast<float(*)[132]>(smem);   // 64x132x4 = 33792 B
#pragma unroll
        for (int mi = 0; mi < 2; ++mi)
#pragma unroll
            for (int ni = 0; ni < 2; ++ni) {
                int rl = wm + mi * 16 + kb * 4;
                int cl = wn + ni * 16 + fr;
#pragma unroll
                for (int r = 0; r < 4; ++r)
                    Red[rl + r][cl] = fmaxf(acc[mi][ni][r], 0.0f);
            }
        __syncthreads();
        int col = tid & 127;
        for (int gg = rb / 25 + (tid >> 7); gg * 25 < rb + 64; gg += 4) {
            int rs = max(gg * 25, rb), re = min(gg * 25 + 25, rb + 64);
            float s = 0.f;
            for (int r = rs; r < re; ++r) s += Red[r - rb][col];
            atomicAdd(&m2[(size_t)gg * 256 + ccol0 + col], s * (1.0f / 25.0f));
        }
    } else {
#pragma unroll
        for (int mi = 0; mi < 2; ++mi)
#pragma unroll
            for (int ni = 0; ni < 2; ++ni) {
                int orow = rb + wm + mi * 16 + kb * 4;
                int ocol = ccol0 + wn + ni * 16 + fr;
#pragma unroll
                for (int r = 0; r < 4; ++r)
                    h10[(size_t)(orow + r) * 256 + ocol] = fmaxf(acc[mi][ni][r], 0.0f);
            }
    }
}

// Tail: layer-2 GEMM (K=256) + row-normalize + FC (r4/r7 frozen).
__launch_bounds__(256)
__global__ void tail_kernel(const float* __restrict__ h10, const float* __restrict__ m2,
                            const float* __restrict__ Wx2, const float* __restrict__ Wn2,
                            const float* __restrict__ fcw, const float* __restrict__ fcb,
                            float* __restrict__ out)
{
    __shared__ float X[4][260];
    __shared__ float M[4][260];
    __shared__ float H[4][260];
    const int tid = threadIdx.x;
    const int r0 = blockIdx.x * 4;

    {
        int r = tid >> 6, q = tid & 63;
        *(float4*)&X[r][q * 4] = *((const float4*)(h10 + (size_t)(r0 + r) * 256) + q);
        *(float4*)&M[r][q * 4] = *((const float4*)(m2 + (size_t)(r0 + r) * 256) + q);
    }
    __syncthreads();

    {
        const float* W = (tid < 128) ? Wx2 : Wn2;
        const float (*S)[260] = (tid < 128) ? X : M;
        int c = tid & 127;
        float acc0 = 0.f, acc1 = 0.f, acc2 = 0.f, acc3 = 0.f;
        for (int k4 = 0; k4 < 256; k4 += 4) {
            float4 s0 = *(const float4*)&S[0][k4];
            float4 s1 = *(const float4*)&S[1][k4];
            float4 s2 = *(const float4*)&S[2][k4];
            float4 s3 = *(const float4*)&S[3][k4];
            float w0 = W[(size_t)(k4 + 0) * 128 + c];
            float w1 = W[(size_t)(k4 + 1) * 128 + c];
            float w2 = W[(size_t)(k4 + 2) * 128 + c];
            float w3 = W[(size_t)(k4 + 3) * 128 + c];
            acc0 = fmaf(s0.x, w0, fmaf(s0.y, w1, fmaf(s0.z, w2, fmaf(s0.w, w3, acc0))));
            acc1 = fmaf(s1.x, w0, fmaf(s1.y, w1, fmaf(s1.z, w2, fmaf(s1.w, w3, acc1))));
            acc2 = fmaf(s2.x, w0, fmaf(s2.y, w1, fmaf(s2.z, w2, fmaf(s2.w, w3, acc2))));
            acc3 = fmaf(s3.x, w0, fmaf(s3.y, w1, fmaf(s3.z, w2, fmaf(s3.w, w3, acc3))));
        }
        H[0][tid] = acc0; H[1][tid] = acc1; H[2][tid] = acc2; H[3][tid] = acc3;
    }
    __syncthreads();

    const int w = tid >> 6, lane = tid & 63;
    float4 hv = *((const float4*)&H[w][0] + lane);
    float ss = hv.x * hv.x + hv.y * hv.y + hv.z * hv.z + hv.w * hv.w;
#pragma unroll
    for (int o = 32; o > 0; o >>= 1) ss += __shfl_xor(ss, o, 64);
    float scale = 1.0f / fmaxf(sqrtf(ss), 1e-12f);

    float acc = 0.f;
    for (int k4 = 0; k4 < 256; k4 += 4) {
        float4 h4 = *(const float4*)&H[w][k4];
        acc = fmaf(h4.x, fcw[(size_t)(k4 + 0) * 64 + lane],
              fmaf(h4.y, fcw[(size_t)(k4 + 1) * 64 + lane],
              fmaf(h4.z, fcw[(size_t)(k4 + 2) * 64 + lane],
              fmaf(h4.w, fcw[(size_t)(k4 + 3) * 64 + lane], acc))));
    }
    out[(size_t)(r0 + w) * 64 + lane] = acc * scale + fcb[lane];
}

extern "C" void kernel_launch(void* const* d_in, const int* in_sizes, int n_in,
                              void* d_out, int out_size, void* d_ws, size_t ws_size,
                              hipStream_t stream)
{
    const int*   ids   = (const int*)d_in[0];
    const float* feats = (const float*)d_in[1];
    const int*   adj   = (const int*)d_in[2];
    const float* W_x1  = (const float*)d_in[3];
    const float* W_n1  = (const float*)d_in[4];
    const float* W_x2  = (const float*)d_in[5];
    const float* W_n2  = (const float*)d_in[6];
    const float* fc_w  = (const float*)d_in[7];
    const float* fc_b  = (const float*)d_in[8];
    float* out = (float*)d_out;

    char* ws = (char*)d_ws;
    int*      ids1 = (int*)(ws + 0);            // 25600 x 4
    int*      ids2 = (int*)(ws + 102400);       // 256000 x 4
    float*    h10  = (float*)(ws + 1126400);    // 1024 x 256 f32
    float*    m2   = (float*)(ws + 2174976);    // 1024 x 256 f32 (atomics)
    uint16_t* xh   = (uint16_t*)(ws + 3223552); // W splits, 32,768 each
    uint16_t* xl   = (uint16_t*)(ws + 3256320);
    uint16_t* nh   = (uint16_t*)(ws + 3289088);
    uint16_t* nl   = (uint16_t*)(ws + 3321856); // end 3,354,624 B

    // JAX PRNG key derivation (threefry2x32, partitionable foldlike):
    uint32_t f0a, f0b, f1a, f1b, s0a, s0b, s1a, s1b;
    tf2x32(0u, 42u, 0u, 0u, f0a, f0b);
    tf2x32(0u, 42u, 0u, 1u, f1a, f1b);
    tf2x32(f0a, f0b, 0u, 1u, s0a, s0b);
    tf2x32(f1a, f1b, 0u, 1u, s1a, s1b);

    // 1) prologue: W splits + ids1 + ids2 + zero m2
    prologue_kernel<<<1484, 256, 0, stream>>>(ids, adj, W_x1, W_n1,
                                              xh, xl, nh, nl,
                                              s0a, s0b, s1a, s1b,
                                              ids1, ids2, (float4*)m2);
    // 2) fused gather+GEMM, BM=64 @ 512 threads (8 waves/block)
    gemm_fused<<<832, 512, 0, stream>>>(feats, ids, ids1, ids2,
                                        xh, xl, nh, nl, m2, h10);
    // 3) tail: layer-2 GEMM + normalize + FC
    tail_kernel<<<256, 256, 0, stream>>>(h10, m2, W_x2, W_n2, fc_w, fc_b, out);
}

// Round 18
// 61.209 us; speedup vs baseline: 1.7920x; 1.0413x over previous
//
#include <hip/hip_runtime.h>
#include <stdint.h>
#include <stddef.h>

// ---------------------------------------------------------------------------
// GraphSAGE supervised forward (B=1024, D=HID=128, fanout 25/10, classes 64)
// Round 18: prologue sampling restructured — one thread per hop-1 row emits
// all 10 hop-2 samples (hop-1 computed once; 10 lookups hit one adj row).
// Fused gemm (BM=64, 512thr) and tail frozen from r17 (63.7us best).
// 3 launches: prologue (484 blk) -> fused gemm (832x512) -> tail.
// ---------------------------------------------------------------------------

typedef short bf16x8v __attribute__((ext_vector_type(8)));
typedef float f32x4v __attribute__((ext_vector_type(4)));

__host__ __device__ inline void tf2x32(uint32_t k0, uint32_t k1,
                                       uint32_t x0, uint32_t x1,
                                       uint32_t &o0, uint32_t &o1)
{
    uint32_t ks2 = k0 ^ k1 ^ 0x1BD11BDAu;
    uint32_t v0 = x0 + k0, v1 = x1 + k1;
#define TFR(d) { v0 += v1; v1 = (v1 << (d)) | (v1 >> (32 - (d))); v1 ^= v0; }
    TFR(13) TFR(15) TFR(26) TFR(6)   v0 += k1;  v1 += ks2 + 1u;
    TFR(17) TFR(29) TFR(16) TFR(24)  v0 += ks2; v1 += k0 + 2u;
    TFR(13) TFR(15) TFR(26) TFR(6)   v0 += k0;  v1 += k1 + 3u;
    TFR(17) TFR(29) TFR(16) TFR(24)  v0 += k1;  v1 += ks2 + 4u;
    TFR(13) TFR(15) TFR(26) TFR(6)   v0 += ks2; v1 += k0 + 5u;
#undef TFR
    o0 = v0; o1 = v1;
}

__device__ inline uint16_t f32_to_bf16_rne(float f)
{
    uint32_t u = __float_as_uint(f);
    u += 0x7FFFu + ((u >> 16) & 1u);
    return (uint16_t)(u >> 16);
}
__device__ inline float bf16_to_f32(uint16_t h)
{
    return __uint_as_float(((uint32_t)h) << 16);
}

// Prologue, one item per thread:
//   [0,32768)       W split-transpose -> xh/xl/nh/nl
//   [32768,98304)   zero m2 (float4)
//   [98304,123904)  j = t-98304: hop-1 -> ids1[j], then 10x hop-2 -> ids2[10j..]
//                   (hop-1 once per row; hop-2 lookups hit one adj row).
__global__ void prologue_kernel(const int* __restrict__ ids, const int* __restrict__ adj,
                                const float* __restrict__ Wx1, const float* __restrict__ Wn1,
                                uint16_t* __restrict__ xh, uint16_t* __restrict__ xl,
                                uint16_t* __restrict__ nh, uint16_t* __restrict__ nl,
                                uint32_t s0a, uint32_t s0b, uint32_t s1a, uint32_t s1b,
                                int* __restrict__ ids1, int* __restrict__ ids2,
                                float4* __restrict__ m2z)
{
    int t = blockIdx.x * 256 + threadIdx.x;
    if (t < 32768) {
        int k = (t & 16383) >> 7, n = t & 127;
        const float* W = (t < 16384) ? Wx1 : Wn1;
        uint16_t* H = (t < 16384) ? xh : nh;
        uint16_t* L = (t < 16384) ? xl : nl;
        float v = W[k * 128 + n];
        uint16_t h = f32_to_bf16_rne(v);
        uint16_t l = f32_to_bf16_rne(v - bf16_to_f32(h));
        H[n * 128 + k] = h;
        L[n * 128 + k] = l;
    } else if (t < 98304) {
        m2z[t - 32768] = make_float4(0.f, 0.f, 0.f, 0.f);
    } else if (t < 123904) {
        int j = t - 98304;                       // hop-1 row [0, 25600)
        uint32_t h, l;
        tf2x32(s0a, s0b, 0u, (uint32_t)j, h, l);
        int s1 = adj[(size_t)ids[j / 25] * 128u + ((h ^ l) & 127u)];
        ids1[j] = s1;
        const int* arow = adj + (size_t)s1 * 128u;
        int* o = ids2 + (size_t)j * 10;
#pragma unroll
        for (int u = 0; u < 10; ++u) {
            uint32_t hh, ll;
            tf2x32(s1a, s1b, 0u, (uint32_t)(j * 10 + u), hh, ll);
            o[u] = arow[(hh ^ ll) & 127u];
        }
    }
}

// Fused gather+GEMM: BM=64, BN=128, K=128, split-bf16 MFMA, 512 thr (8 waves).
// vb<400: z1 (mean10 inline, heavy, first); vb<416: z3 (mean25 inline);
// vb<816: z0 (gather ids1); else z2 (gather ids).
// z0/z1 -> mean25 epilogue atomicAdd m2; z2/z3 -> relu write h10. (r17 frozen)
__launch_bounds__(512)
__global__ void gemm_fused(const float* __restrict__ feats, const int* __restrict__ ids,
                           const int* __restrict__ ids1, const int* __restrict__ ids2,
                           const uint16_t* __restrict__ xh, const uint16_t* __restrict__ xl,
                           const uint16_t* __restrict__ nh, const uint16_t* __restrict__ nl,
                           float* __restrict__ m2, float* __restrict__ h10)
{
    __shared__ __align__(16) char smem[34816];
    uint16_t (*Ahi)[136] = reinterpret_cast<uint16_t(*)[136]>(smem);
    uint16_t (*Alo)[136] = reinterpret_cast<uint16_t(*)[136]>(smem + 17408);

    const int tid = threadIdx.x;
    const int vb = blockIdx.x;
    int z, bx;
    if (vb < 400)      { z = 1; bx = vb; }
    else if (vb < 416) { z = 3; bx = vb - 400; }
    else if (vb < 816) { z = 0; bx = vb - 416; }
    else               { z = 2; bx = vb - 816; }
    const int rb = bx * 64;
    const bool isX = (z == 0) || (z == 2);
    const uint16_t* WH = isX ? xh : nh;
    const uint16_t* WL = isX ? xl : nl;
    const int ccol0 = isX ? 0 : 128;

    const int lane = tid & 63;
    const int wv = tid >> 6;            // 0..7

    // ---- stage A (64 rows x 128 k = 2048 float4 chunks, bf16 hi/lo) ----
    if (isX) {                          // row gather + split: 4 chunks/thread
        const int* g = (z == 0) ? ids1 : ids;
#pragma unroll
        for (int i = 0; i < 4; ++i) {
            int s = tid + i * 512;      // 0..2047
            int row = s >> 5, f4 = s & 31, k0 = f4 * 4;
            size_t arow = (size_t)g[rb + row];
            float4 v = *(const float4*)(feats + arow * 128 + k0);
            uint16_t h0 = f32_to_bf16_rne(v.x), h1 = f32_to_bf16_rne(v.y);
            uint16_t h2 = f32_to_bf16_rne(v.z), h3 = f32_to_bf16_rne(v.w);
            *(ushort4*)&Ahi[row][k0] = make_ushort4(h0, h1, h2, h3);
            *(ushort4*)&Alo[row][k0] = make_ushort4(f32_to_bf16_rne(v.x - bf16_to_f32(h0)),
                                                    f32_to_bf16_rne(v.y - bf16_to_f32(h1)),
                                                    f32_to_bf16_rne(v.z - bf16_to_f32(h2)),
                                                    f32_to_bf16_rne(v.w - bf16_to_f32(h3)));
        }
    } else {
        // inline mean: 16 half-waves, each owns 4 rows; idv hoisted.
        const int h = lane & 31;
        const int hw = tid >> 5;        // 0..15
        const int FAN = (z == 1) ? 10 : 25;
        const int* src = (z == 1) ? ids2 : ids1;
        const float sc = (z == 1) ? 0.1f : (1.0f / 25.0f);
        int idv[4];
#pragma unroll
        for (int j = 0; j < 4; ++j) {
            int r = rb + hw * 4 + j;
            idv[j] = (h < FAN) ? src[(size_t)r * FAN + h] : 0;
        }
#pragma unroll
        for (int j = 0; j < 4; ++j) {
            float a0 = 0.f, a1 = 0.f, a2 = 0.f, a3 = 0.f;
            if (z == 1) {
#pragma unroll
                for (int t = 0; t < 10; ++t) {
                    int id = __shfl(idv[j], (lane & 32) + t, 64);
                    float4 vv = *((const float4*)(feats + (size_t)id * 128) + h);
                    a0 += vv.x; a1 += vv.y; a2 += vv.z; a3 += vv.w;
                }
            } else {
#pragma unroll
                for (int t = 0; t < 25; ++t) {
                    int id = __shfl(idv[j], (lane & 32) + t, 64);
                    float4 vv = *((const float4*)(feats + (size_t)id * 128) + h);
                    a0 += vv.x; a1 += vv.y; a2 += vv.z; a3 += vv.w;
                }
            }
            a0 *= sc; a1 *= sc; a2 *= sc; a3 *= sc;
            uint16_t b0 = f32_to_bf16_rne(a0), b1 = f32_to_bf16_rne(a1);
            uint16_t b2 = f32_to_bf16_rne(a2), b3 = f32_to_bf16_rne(a3);
            int row = hw * 4 + j;
            *(ushort4*)&Ahi[row][h * 4] = make_ushort4(b0, b1, b2, b3);
            *(ushort4*)&Alo[row][h * 4] =
                make_ushort4(f32_to_bf16_rne(a0 - bf16_to_f32(b0)),
                             f32_to_bf16_rne(a1 - bf16_to_f32(b1)),
                             f32_to_bf16_rne(a2 - bf16_to_f32(b2)),
                             f32_to_bf16_rne(a3 - bf16_to_f32(b3)));
        }
    }
    __syncthreads();

    // ---- MFMA: 8 waves in 2x4 grid; each wave 32(M) x 32(N) ----
    const int wm = (wv >> 2) * 32;
    const int wn = (wv & 3) * 32;
    const int fr = lane & 15;
    const int kb = lane >> 4;

    f32x4v acc[2][2] = {};
#pragma unroll
    for (int ks = 0; ks < 4; ++ks) {
        const int kk = ks * 32 + kb * 8;
        bf16x8v aH[2], aL[2];
#pragma unroll
        for (int mi = 0; mi < 2; ++mi) {
            aH[mi] = *(const bf16x8v*)&Ahi[wm + mi * 16 + fr][kk];
            aL[mi] = *(const bf16x8v*)&Alo[wm + mi * 16 + fr][kk];
        }
#pragma unroll
        for (int ni = 0; ni < 2; ++ni) {
            size_t wrow = (size_t)(wn + ni * 16 + fr) * 128 + kk;
            bf16x8v bH = *(const bf16x8v*)(WH + wrow);
            bf16x8v bL = *(const bf16x8v*)(WL + wrow);
#pragma unroll
            for (int mi = 0; mi < 2; ++mi) {
                acc[mi][ni] = __builtin_amdgcn_mfma_f32_16x16x32_bf16(aH[mi], bH, acc[mi][ni], 0, 0, 0);
                acc[mi][ni] = __builtin_amdgcn_mfma_f32_16x16x32_bf16(aH[mi], bL, acc[mi][ni], 0, 0, 0);
                acc[mi][ni] = __builtin_amdgcn_mfma_f32_16x16x32_bf16(aL[mi], bH, acc[mi][ni], 0, 0, 0);
            }
        }
    }

    // C/D layout: col = fr, row = kb*4 + reg.
    if (z < 2) {
        __syncthreads();
        float (*Red)[132] = reinterpret_cast<float(*)[132]>(smem);   // 64x132x4 = 33792 B
#pragma unroll
        for (int mi = 0; mi < 2; ++mi)
#pragma unroll
            for (int ni = 0; ni < 2; ++ni) {
                int rl = wm + mi * 16 + kb * 4;
                int cl = wn + ni * 16 + fr;
#pragma unroll
                for (int r = 0; r < 4; ++r)
                    Red[rl + r][cl] = fmaxf(acc[mi][ni][r], 0.0f);
            }
        __syncthreads();
        int col = tid & 127;
        for (int gg = rb / 25 + (tid >> 7); gg * 25 < rb + 64; gg += 4) {
            int rs = max(gg * 25, rb), re = min(gg * 25 + 25, rb + 64);
            float s = 0.f;
            for (int r = rs; r < re; ++r) s += Red[r - rb][col];
            atomicAdd(&m2[(size_t)gg * 256 + ccol0 + col], s * (1.0f / 25.0f));
        }
    } else {
#pragma unroll
        for (int mi = 0; mi < 2; ++mi)
#pragma unroll
            for (int ni = 0; ni < 2; ++ni) {
                int orow = rb + wm + mi * 16 + kb * 4;
                int ocol = ccol0 + wn + ni * 16 + fr;
#pragma unroll
                for (int r = 0; r < 4; ++r)
                    h10[(size_t)(orow + r) * 256 + ocol] = fmaxf(acc[mi][ni][r], 0.0f);
            }
    }
}

// Tail: layer-2 GEMM (K=256) + row-normalize + FC (r4/r7 frozen).
__launch_bounds__(256)
__global__ void tail_kernel(const float* __restrict__ h10, const float* __restrict__ m2,
                            const float* __restrict__ Wx2, const float* __restrict__ Wn2,
                            const float* __restrict__ fcw, const float* __restrict__ fcb,
                            float* __restrict__ out)
{
    __shared__ float X[4][260];
    __shared__ float M[4][260];
    __shared__ float H[4][260];
    const int tid = threadIdx.x;
    const int r0 = blockIdx.x * 4;

    {
        int r = tid >> 6, q = tid & 63;
        *(float4*)&X[r][q * 4] = *((const float4*)(h10 + (size_t)(r0 + r) * 256) + q);
        *(float4*)&M[r][q * 4] = *((const float4*)(m2 + (size_t)(r0 + r) * 256) + q);
    }
    __syncthreads();

    {
        const float* W = (tid < 128) ? Wx2 : Wn2;
        const float (*S)[260] = (tid < 128) ? X : M;
        int c = tid & 127;
        float acc0 = 0.f, acc1 = 0.f, acc2 = 0.f, acc3 = 0.f;
        for (int k4 = 0; k4 < 256; k4 += 4) {
            float4 s0 = *(const float4*)&S[0][k4];
            float4 s1 = *(const float4*)&S[1][k4];
            float4 s2 = *(const float4*)&S[2][k4];
            float4 s3 = *(const float4*)&S[3][k4];
            float w0 = W[(size_t)(k4 + 0) * 128 + c];
            float w1 = W[(size_t)(k4 + 1) * 128 + c];
            float w2 = W[(size_t)(k4 + 2) * 128 + c];
            float w3 = W[(size_t)(k4 + 3) * 128 + c];
            acc0 = fmaf(s0.x, w0, fmaf(s0.y, w1, fmaf(s0.z, w2, fmaf(s0.w, w3, acc0))));
            acc1 = fmaf(s1.x, w0, fmaf(s1.y, w1, fmaf(s1.z, w2, fmaf(s1.w, w3, acc1))));
            acc2 = fmaf(s2.x, w0, fmaf(s2.y, w1, fmaf(s2.z, w2, fmaf(s2.w, w3, acc2))));
            acc3 = fmaf(s3.x, w0, fmaf(s3.y, w1, fmaf(s3.z, w2, fmaf(s3.w, w3, acc3))));
        }
        H[0][tid] = acc0; H[1][tid] = acc1; H[2][tid] = acc2; H[3][tid] = acc3;
    }
    __syncthreads();

    const int w = tid >> 6, lane = tid & 63;
    float4 hv = *((const float4*)&H[w][0] + lane);
    float ss = hv.x * hv.x + hv.y * hv.y + hv.z * hv.z + hv.w * hv.w;
#pragma unroll
    for (int o = 32; o > 0; o >>= 1) ss += __shfl_xor(ss, o, 64);
    float scale = 1.0f / fmaxf(sqrtf(ss), 1e-12f);

    float acc = 0.f;
    for (int k4 = 0; k4 < 256; k4 += 4) {
        float4 h4 = *(const float4*)&H[w][k4];
        acc = fmaf(h4.x, fcw[(size_t)(k4 + 0) * 64 + lane],
              fmaf(h4.y, fcw[(size_t)(k4 + 1) * 64 + lane],
              fmaf(h4.z, fcw[(size_t)(k4 + 2) * 64 + lane],
              fmaf(h4.w, fcw[(size_t)(k4 + 3) * 64 + lane], acc))));
    }
    out[(size_t)(r0 + w) * 64 + lane] = acc * scale + fcb[lane];
}

extern "C" void kernel_launch(void* const* d_in, const int* in_sizes, int n_in,
                              void* d_out, int out_size, void* d_ws, size_t ws_size,
                              hipStream_t stream)
{
    const int*   ids   = (const int*)d_in[0];
    const float* feats = (const float*)d_in[1];
    const int*   adj   = (const int*)d_in[2];
    const float* W_x1  = (const float*)d_in[3];
    const float* W_n1  = (const float*)d_in[4];
    const float* W_x2  = (const float*)d_in[5];
    const float* W_n2  = (const float*)d_in[6];
    const float* fc_w  = (const float*)d_in[7];
    const float* fc_b  = (const float*)d_in[8];
    float* out = (float*)d_out;

    char* ws = (char*)d_ws;
    int*      ids1 = (int*)(ws + 0);            // 25600 x 4
    int*      ids2 = (int*)(ws + 102400);       // 256000 x 4
    float*    h10  = (float*)(ws + 1126400);    // 1024 x 256 f32
    float*    m2   = (float*)(ws + 2174976);    // 1024 x 256 f32 (atomics)
    uint16_t* xh   = (uint16_t*)(ws + 3223552); // W splits, 32,768 each
    uint16_t* xl   = (uint16_t*)(ws + 3256320);
    uint16_t* nh   = (uint16_t*)(ws + 3289088);
    uint16_t* nl   = (uint16_t*)(ws + 3321856); // end 3,354,624 B

    // JAX PRNG key derivation (threefry2x32, partitionable foldlike):
    uint32_t f0a, f0b, f1a, f1b, s0a, s0b, s1a, s1b;
    tf2x32(0u, 42u, 0u, 0u, f0a, f0b);
    tf2x32(0u, 42u, 0u, 1u, f1a, f1b);
    tf2x32(f0a, f0b, 0u, 1u, s0a, s0b);
    tf2x32(f1a, f1b, 0u, 1u, s1a, s1b);

    // 1) prologue: W splits + m2 zero + per-row hop-1 & hop-2 sampling
    prologue_kernel<<<484, 256, 0, stream>>>(ids, adj, W_x1, W_n1,
                                             xh, xl, nh, nl,
                                             s0a, s0b, s1a, s1b,
                                             ids1, ids2, (float4*)m2);
    // 2) fused gather+GEMM, BM=64 @ 512 threads (8 waves/block)
    gemm_fused<<<832, 512, 0, stream>>>(feats, ids, ids1, ids2,
                                        xh, xl, nh, nl, m2, h10);
    // 3) tail: layer-2 GEMM + normalize + FC
    tail_kernel<<<256, 256, 0, stream>>>(h10, m2, W_x2, W_n2, fc_w, fc_b, out);
}